// Round 1
// baseline (1367.170 us; speedup 1.0000x reference)
//
#include <hip/hip_runtime.h>
#include <hip/hip_bf16.h>

// Problem constants
#define NB    65536      // batch rows
#define KDIM  1024       // reduction dim for all projections
#define NDIM  1024       // output dim per projection

typedef float f32x4 __attribute__((ext_vector_type(4)));
typedef short short8 __attribute__((ext_vector_type(8)));
typedef unsigned short ushort8v __attribute__((ext_vector_type(8)));

static __device__ __forceinline__ unsigned short f2bf(float f) {
    union { float f; unsigned u; } v; v.f = f;
    unsigned r = v.u + 0x7FFFu + ((v.u >> 16) & 1u);
    return (unsigned short)(r >> 16);
}
static __device__ __forceinline__ float bf2f(unsigned short h) {
    union { unsigned u; float f; } v; v.u = ((unsigned)h) << 16;
    return v.f;
}

// ---------------------------------------------------------------------------
// fp32 -> bf16 convert (weights), 4 elems/thread
// ---------------------------------------------------------------------------
__global__ __launch_bounds__(256) void f32_to_bf16_k(
    const float* __restrict__ s, unsigned short* __restrict__ d, int n4)
{
    int i = blockIdx.x * 256 + threadIdx.x;
    if (i < n4) {
        float4 v = reinterpret_cast<const float4*>(s)[i];
        ushort4 o;
        o.x = f2bf(v.x); o.y = f2bf(v.y); o.z = f2bf(v.z); o.w = f2bf(v.w);
        reinterpret_cast<ushort4*>(d)[i] = o;
    }
}

// ---------------------------------------------------------------------------
// GEMM: C[M,N] = A[M,K] @ W[N,K]^T (+bias), MFMA 16x16x32 bf16
// 128x128 tile, BK=32, 4 waves (2x2), reg-staged LDS with +8 pad
// A_F32: A is fp32 (convert during staging) else bf16
// OUT_F32: write fp32 with bias, else write bf16
// ---------------------------------------------------------------------------
template<int A_F32, int OUT_F32>
__global__ __launch_bounds__(256) void gemm_bt(
    const void* __restrict__ Aptr, const unsigned short* __restrict__ W,
    const float* __restrict__ bias, void* __restrict__ Cptr)
{
    constexpr int K = KDIM, N = NDIM;
    __shared__ alignas(16) unsigned short As[128][40];
    __shared__ alignas(16) unsigned short Bs[128][40];

    const int t    = threadIdx.x;
    const int lane = t & 63;
    const int wid  = t >> 6;
    const int wr   = wid >> 1;        // wave row (0..1), 64 rows each
    const int wc   = wid & 1;         // wave col (0..1), 64 cols each
    const int bn0  = blockIdx.x * 128;
    const int bm0  = blockIdx.y * 128;
    const int frow = lane & 15;
    const int fk   = (lane >> 4) * 8;

    f32x4 acc[4][4];
#pragma unroll
    for (int mi = 0; mi < 4; ++mi)
#pragma unroll
        for (int ni = 0; ni < 4; ++ni)
            acc[mi][ni] = (f32x4){0.f, 0.f, 0.f, 0.f};

    for (int kk = 0; kk < K; kk += 32) {
        __syncthreads();
        // ---- stage A tile [128 x 32] -> bf16 LDS
        if (A_F32) {
            const float* A = (const float*)Aptr;
#pragma unroll
            for (int it = 0; it < 4; ++it) {
                int row = (t >> 3) + it * 32;
                int col = (t & 7) * 4;
                float4 v = *reinterpret_cast<const float4*>(
                    &A[(size_t)(bm0 + row) * K + kk + col]);
                ushort4 o;
                o.x = f2bf(v.x); o.y = f2bf(v.y); o.z = f2bf(v.z); o.w = f2bf(v.w);
                *reinterpret_cast<ushort4*>(&As[row][col]) = o;
            }
        } else {
            const unsigned short* A = (const unsigned short*)Aptr;
#pragma unroll
            for (int it = 0; it < 2; ++it) {
                int row = (t >> 2) + it * 64;
                int col = (t & 3) * 8;
                ushort8v v = *reinterpret_cast<const ushort8v*>(
                    &A[(size_t)(bm0 + row) * K + kk + col]);
                *reinterpret_cast<ushort8v*>(&As[row][col]) = v;
            }
        }
        // ---- stage B tile: W rows [bn0..bn0+128) x [kk..kk+32), bf16
#pragma unroll
        for (int it = 0; it < 2; ++it) {
            int row = (t >> 2) + it * 64;
            int col = (t & 3) * 8;
            ushort8v v = *reinterpret_cast<const ushort8v*>(
                &W[(size_t)(bn0 + row) * K + kk + col]);
            *reinterpret_cast<ushort8v*>(&Bs[row][col]) = v;
        }
        __syncthreads();

        short8 a[4], b[4];
#pragma unroll
        for (int mi = 0; mi < 4; ++mi)
            a[mi] = *reinterpret_cast<const short8*>(&As[wr * 64 + mi * 16 + frow][fk]);
#pragma unroll
        for (int ni = 0; ni < 4; ++ni)
            b[ni] = *reinterpret_cast<const short8*>(&Bs[wc * 64 + ni * 16 + frow][fk]);
#pragma unroll
        for (int mi = 0; mi < 4; ++mi)
#pragma unroll
            for (int ni = 0; ni < 4; ++ni)
                acc[mi][ni] = __builtin_amdgcn_mfma_f32_16x16x32_bf16(
                    a[mi], b[ni], acc[mi][ni], 0, 0, 0);
    }

    // ---- epilogue: D row = (lane>>4)*4 + r, col = lane&15  [m89-verified]
    const int crow = (lane >> 4) * 4;
    const int ccol = lane & 15;
    if (OUT_F32) {
        float* Cf = (float*)Cptr;
        float bv[4];
#pragma unroll
        for (int ni = 0; ni < 4; ++ni)
            bv[ni] = bias[bn0 + wc * 64 + ni * 16 + ccol];
#pragma unroll
        for (int mi = 0; mi < 4; ++mi)
#pragma unroll
            for (int ni = 0; ni < 4; ++ni) {
                size_t base = (size_t)(bm0 + wr * 64 + mi * 16 + crow) * N
                            + (bn0 + wc * 64 + ni * 16 + ccol);
#pragma unroll
                for (int r = 0; r < 4; ++r)
                    Cf[base + (size_t)r * N] = acc[mi][ni][r] + bv[ni];
            }
    } else {
        unsigned short* Cb = (unsigned short*)Cptr;
#pragma unroll
        for (int mi = 0; mi < 4; ++mi)
#pragma unroll
            for (int ni = 0; ni < 4; ++ni) {
                size_t base = (size_t)(bm0 + wr * 64 + mi * 16 + crow) * N
                            + (bn0 + wc * 64 + ni * 16 + ccol);
#pragma unroll
                for (int r = 0; r < 4; ++r)
                    Cb[base + (size_t)r * N] = f2bf(acc[mi][ni][r]);
            }
    }
}

// ---------------------------------------------------------------------------
// Per-row attention: scores[16,16] = Q K^T * 1/8, softmax, feats = P V.
// 1 wave per row, 4 waves/block. K,V rows staged in LDS.
// lane -> (h = lane>>2, sub = lane&3); lane owns d in [sub*16, sub*16+16).
// feats written over the Q buffer (same rows, read-before-write within wave).
// ---------------------------------------------------------------------------
__global__ __launch_bounds__(256) void attn_k(
    const unsigned short* __restrict__ Qb, const unsigned short* __restrict__ Kb,
    const unsigned short* __restrict__ Vb, unsigned short* __restrict__ Fb)
{
    __shared__ alignas(16) unsigned short KL[4][1024];
    __shared__ alignas(16) unsigned short VL[4][1024];
    const int t = threadIdx.x;
    const int lane = t & 63;
    const int wid = t >> 6;
    const size_t row = (size_t)blockIdx.x * 4 + wid;
    const size_t base = row * 1024;
    const int off = lane * 16;

    // Q chunk for this lane: Q[h][sub*16 .. +16) == elements [lane*16, +16)
    ushort8v q0 = *reinterpret_cast<const ushort8v*>(&Qb[base + off]);
    ushort8v q1 = *reinterpret_cast<const ushort8v*>(&Qb[base + off + 8]);
    float qf[16];
#pragma unroll
    for (int j = 0; j < 8; ++j) { qf[j] = bf2f(q0[j]); qf[8 + j] = bf2f(q1[j]); }

    // stage K,V rows
    *reinterpret_cast<ushort8v*>(&KL[wid][off])     = *reinterpret_cast<const ushort8v*>(&Kb[base + off]);
    *reinterpret_cast<ushort8v*>(&KL[wid][off + 8]) = *reinterpret_cast<const ushort8v*>(&Kb[base + off + 8]);
    *reinterpret_cast<ushort8v*>(&VL[wid][off])     = *reinterpret_cast<const ushort8v*>(&Vb[base + off]);
    *reinterpret_cast<ushort8v*>(&VL[wid][off + 8]) = *reinterpret_cast<const ushort8v*>(&Vb[base + off + 8]);
    __syncthreads();

    const int sub = lane & 3;
    float s[16];
#pragma unroll
    for (int g = 0; g < 16; ++g) {
        const ushort8v k0 = *reinterpret_cast<const ushort8v*>(&KL[wid][g * 64 + sub * 16]);
        const ushort8v k1 = *reinterpret_cast<const ushort8v*>(&KL[wid][g * 64 + sub * 16 + 8]);
        float acc = 0.f;
#pragma unroll
        for (int j = 0; j < 8; ++j)
            acc += qf[j] * bf2f(k0[j]) + qf[8 + j] * bf2f(k1[j]);
        s[g] = acc;
    }
    // reduce partial dots across the 4-lane d-group
#pragma unroll
    for (int m = 1; m <= 2; m <<= 1)
#pragma unroll
        for (int g = 0; g < 16; ++g)
            s[g] += __shfl_xor(s[g], m, 64);

    float mx = s[0];
#pragma unroll
    for (int g = 1; g < 16; ++g) mx = fmaxf(mx, s[g]);
    float p[16], denom = 0.f;
#pragma unroll
    for (int g = 0; g < 16; ++g) {
        p[g] = __expf((s[g] - mx) * 0.125f);
        denom += p[g];
    }
    float inv = 1.f / denom;

    float f[16];
#pragma unroll
    for (int j = 0; j < 16; ++j) f[j] = 0.f;
#pragma unroll
    for (int g = 0; g < 16; ++g) {
        float pg = p[g] * inv;
        const ushort8v v0 = *reinterpret_cast<const ushort8v*>(&VL[wid][g * 64 + sub * 16]);
        const ushort8v v1 = *reinterpret_cast<const ushort8v*>(&VL[wid][g * 64 + sub * 16 + 8]);
#pragma unroll
        for (int j = 0; j < 8; ++j) {
            f[j]     += pg * bf2f(v0[j]);
            f[8 + j] += pg * bf2f(v1[j]);
        }
    }
    ushort8v o0, o1;
#pragma unroll
    for (int j = 0; j < 8; ++j) { o0[j] = f2bf(f[j]); o1[j] = f2bf(f[8 + j]); }
    *reinterpret_cast<ushort8v*>(&Fb[base + off])     = o0;
    *reinterpret_cast<ushort8v*>(&Fb[base + off + 8]) = o1;
}

// ---------------------------------------------------------------------------
extern "C" void kernel_launch(void* const* d_in, const int* in_sizes, int n_in,
                              void* d_out, int out_size, void* d_ws, size_t ws_size,
                              hipStream_t stream)
{
    (void)in_sizes; (void)n_in; (void)out_size; (void)ws_size;
    const float* latent = (const float*)d_in[0];
    const float* cond   = (const float*)d_in[1];
    const float* Wq     = (const float*)d_in[2];
    const float* Wk     = (const float*)d_in[3];
    const float* Wv     = (const float*)d_in[4];
    const float* Wout   = (const float*)d_in[5];
    const float* bout   = (const float*)d_in[6];
    float* out = (float*)d_out;

    char* ws = (char*)d_ws;
    const size_t MB = 1ull << 20;
    unsigned short* wqb = (unsigned short*)(ws + 0 * MB);
    unsigned short* wkb = (unsigned short*)(ws + 2 * MB);
    unsigned short* wvb = (unsigned short*)(ws + 4 * MB);
    unsigned short* wob = (unsigned short*)(ws + 6 * MB);
    unsigned short* Qb  = (unsigned short*)(ws + 8 * MB);             // 128 MB, becomes feats
    unsigned short* Kbf = (unsigned short*)(ws + 8 * MB + 128 * MB);  // 128 MB
    unsigned short* Vbf = (unsigned short*)(ws + 8 * MB + 256 * MB);  // 128 MB

    const int n4 = (KDIM * NDIM) / 4;
    f32_to_bf16_k<<<1024, 256, 0, stream>>>(Wq,   wqb, n4);
    f32_to_bf16_k<<<1024, 256, 0, stream>>>(Wk,   wkb, n4);
    f32_to_bf16_k<<<1024, 256, 0, stream>>>(Wv,   wvb, n4);
    f32_to_bf16_k<<<1024, 256, 0, stream>>>(Wout, wob, n4);

    dim3 ggrid(NDIM / 128, NB / 128);  // (8, 512)
    gemm_bt<1, 0><<<ggrid, 256, 0, stream>>>(latent, wqb, nullptr, Qb);
    gemm_bt<1, 0><<<ggrid, 256, 0, stream>>>(cond,   wkb, nullptr, Kbf);
    gemm_bt<1, 0><<<ggrid, 256, 0, stream>>>(cond,   wvb, nullptr, Vbf);

    attn_k<<<NB / 4, 256, 0, stream>>>(Qb, Kbf, Vbf, Qb);

    gemm_bt<0, 1><<<ggrid, 256, 0, stream>>>(Qb, wob, bout, out);
}

// Round 2
// 1363.687 us; speedup vs baseline: 1.0026x; 1.0026x over previous
//
#include <hip/hip_runtime.h>
#include <hip/hip_bf16.h>

// Problem constants
#define NB    65536      // batch rows
#define KDIM  1024       // reduction dim for all projections
#define NDIM  1024       // output dim per projection

typedef float f32x4 __attribute__((ext_vector_type(4)));
typedef short short8 __attribute__((ext_vector_type(8)));
typedef unsigned short ushort8v __attribute__((ext_vector_type(8)));

static __device__ __forceinline__ unsigned short f2bf(float f) {
    union { float f; unsigned u; } v; v.f = f;
    unsigned r = v.u + 0x7FFFu + ((v.u >> 16) & 1u);
    return (unsigned short)(r >> 16);
}
static __device__ __forceinline__ float bf2f(unsigned short h) {
    union { unsigned u; float f; } v; v.u = ((unsigned)h) << 16;
    return v.f;
}

// ---------------------------------------------------------------------------
// fp32 -> bf16 convert (weights), 4 elems/thread
// ---------------------------------------------------------------------------
__global__ __launch_bounds__(256) void f32_to_bf16_k(
    const float* __restrict__ s, unsigned short* __restrict__ d, int n4)
{
    int i = blockIdx.x * 256 + threadIdx.x;
    if (i < n4) {
        float4 v = reinterpret_cast<const float4*>(s)[i];
        ushort4 o;
        o.x = f2bf(v.x); o.y = f2bf(v.y); o.z = f2bf(v.z); o.w = f2bf(v.w);
        reinterpret_cast<ushort4*>(d)[i] = o;
    }
}

// ---------------------------------------------------------------------------
// GEMM: C[M,N] = A[M,K] @ W[N,K]^T (+bias), MFMA 16x16x32 bf16
// 128x128 tile, BK=32, 4 waves (2x2), reg-staged LDS with +8 pad
// A_F32: A is fp32 (convert during staging) else bf16
// OUT_F32: write fp32 with bias, else write bf16
// ---------------------------------------------------------------------------
template<int A_F32, int OUT_F32>
__global__ __launch_bounds__(256) void gemm_bt(
    const void* __restrict__ Aptr, const unsigned short* __restrict__ W,
    const float* __restrict__ bias, void* __restrict__ Cptr)
{
    constexpr int K = KDIM, N = NDIM;
    __shared__ alignas(16) unsigned short As[128][40];
    __shared__ alignas(16) unsigned short Bs[128][40];

    const int t    = threadIdx.x;
    const int lane = t & 63;
    const int wid  = t >> 6;
    const int wr   = wid >> 1;        // wave row (0..1), 64 rows each
    const int wc   = wid & 1;         // wave col (0..1), 64 cols each
    const int bn0  = blockIdx.x * 128;
    const int bm0  = blockIdx.y * 128;
    const int frow = lane & 15;
    const int fk   = (lane >> 4) * 8;

    f32x4 acc[4][4];
#pragma unroll
    for (int mi = 0; mi < 4; ++mi)
#pragma unroll
        for (int ni = 0; ni < 4; ++ni)
            acc[mi][ni] = (f32x4){0.f, 0.f, 0.f, 0.f};

    for (int kk = 0; kk < K; kk += 32) {
        __syncthreads();
        // ---- stage A tile [128 x 32] -> bf16 LDS
        if (A_F32) {
            const float* A = (const float*)Aptr;
#pragma unroll
            for (int it = 0; it < 4; ++it) {
                int row = (t >> 3) + it * 32;
                int col = (t & 7) * 4;
                float4 v = *reinterpret_cast<const float4*>(
                    &A[(size_t)(bm0 + row) * K + kk + col]);
                ushort4 o;
                o.x = f2bf(v.x); o.y = f2bf(v.y); o.z = f2bf(v.z); o.w = f2bf(v.w);
                *reinterpret_cast<ushort4*>(&As[row][col]) = o;
            }
        } else {
            const unsigned short* A = (const unsigned short*)Aptr;
#pragma unroll
            for (int it = 0; it < 2; ++it) {
                int row = (t >> 2) + it * 64;
                int col = (t & 3) * 8;
                ushort8v v = *reinterpret_cast<const ushort8v*>(
                    &A[(size_t)(bm0 + row) * K + kk + col]);
                *reinterpret_cast<ushort8v*>(&As[row][col]) = v;
            }
        }
        // ---- stage B tile: W rows [bn0..bn0+128) x [kk..kk+32), bf16
#pragma unroll
        for (int it = 0; it < 2; ++it) {
            int row = (t >> 2) + it * 64;
            int col = (t & 3) * 8;
            ushort8v v = *reinterpret_cast<const ushort8v*>(
                &W[(size_t)(bn0 + row) * K + kk + col]);
            *reinterpret_cast<ushort8v*>(&Bs[row][col]) = v;
        }
        __syncthreads();

        short8 a[4], b[4];
#pragma unroll
        for (int mi = 0; mi < 4; ++mi)
            a[mi] = *reinterpret_cast<const short8*>(&As[wr * 64 + mi * 16 + frow][fk]);
#pragma unroll
        for (int ni = 0; ni < 4; ++ni)
            b[ni] = *reinterpret_cast<const short8*>(&Bs[wc * 64 + ni * 16 + frow][fk]);
#pragma unroll
        for (int mi = 0; mi < 4; ++mi)
#pragma unroll
            for (int ni = 0; ni < 4; ++ni)
                acc[mi][ni] = __builtin_amdgcn_mfma_f32_16x16x32_bf16(
                    a[mi], b[ni], acc[mi][ni], 0, 0, 0);
    }

    // ---- epilogue: D row = (lane>>4)*4 + r, col = lane&15  [m89-verified]
    const int crow = (lane >> 4) * 4;
    const int ccol = lane & 15;
    if (OUT_F32) {
        float* Cf = (float*)Cptr;
        float bv[4];
#pragma unroll
        for (int ni = 0; ni < 4; ++ni)
            bv[ni] = bias[bn0 + wc * 64 + ni * 16 + ccol];
#pragma unroll
        for (int mi = 0; mi < 4; ++mi)
#pragma unroll
            for (int ni = 0; ni < 4; ++ni) {
                size_t base = (size_t)(bm0 + wr * 64 + mi * 16 + crow) * N
                            + (bn0 + wc * 64 + ni * 16 + ccol);
#pragma unroll
                for (int r = 0; r < 4; ++r)
                    Cf[base + (size_t)r * N] = acc[mi][ni][r] + bv[ni];
            }
    } else {
        unsigned short* Cb = (unsigned short*)Cptr;
#pragma unroll
        for (int mi = 0; mi < 4; ++mi)
#pragma unroll
            for (int ni = 0; ni < 4; ++ni) {
                size_t base = (size_t)(bm0 + wr * 64 + mi * 16 + crow) * N
                            + (bn0 + wc * 64 + ni * 16 + ccol);
#pragma unroll
                for (int r = 0; r < 4; ++r)
                    Cb[base + (size_t)r * N] = f2bf(acc[mi][ni][r]);
            }
    }
}

// ---------------------------------------------------------------------------
// Per-row attention: scores[16,16] = Q K^T * 1/8, softmax, feats = P V.
// 1 wave per row, 4 waves/block. K,V rows staged in LDS.
// lane -> (h = lane>>2, sub = lane&3); lane owns d in [sub*16, sub*16+16).
// feats written over the Q buffer (same rows, read-before-write within wave).
// ---------------------------------------------------------------------------
__global__ __launch_bounds__(256) void attn_k(
    const unsigned short* __restrict__ Qb, const unsigned short* __restrict__ Kb,
    const unsigned short* __restrict__ Vb, unsigned short* __restrict__ Fb)
{
    __shared__ alignas(16) unsigned short KL[4][1024];
    __shared__ alignas(16) unsigned short VL[4][1024];
    const int t = threadIdx.x;
    const int lane = t & 63;
    const int wid = t >> 6;
    const size_t row = (size_t)blockIdx.x * 4 + wid;
    const size_t base = row * 1024;
    const int off = lane * 16;

    // Q chunk for this lane: Q[h][sub*16 .. +16) == elements [lane*16, +16)
    ushort8v q0 = *reinterpret_cast<const ushort8v*>(&Qb[base + off]);
    ushort8v q1 = *reinterpret_cast<const ushort8v*>(&Qb[base + off + 8]);
    float qf[16];
#pragma unroll
    for (int j = 0; j < 8; ++j) { qf[j] = bf2f(q0[j]); qf[8 + j] = bf2f(q1[j]); }

    // stage K,V rows
    *reinterpret_cast<ushort8v*>(&KL[wid][off])     = *reinterpret_cast<const ushort8v*>(&Kb[base + off]);
    *reinterpret_cast<ushort8v*>(&KL[wid][off + 8]) = *reinterpret_cast<const ushort8v*>(&Kb[base + off + 8]);
    *reinterpret_cast<ushort8v*>(&VL[wid][off])     = *reinterpret_cast<const ushort8v*>(&Vb[base + off]);
    *reinterpret_cast<ushort8v*>(&VL[wid][off + 8]) = *reinterpret_cast<const ushort8v*>(&Vb[base + off + 8]);
    __syncthreads();

    const int sub = lane & 3;
    float s[16];
#pragma unroll
    for (int g = 0; g < 16; ++g) {
        const ushort8v k0 = *reinterpret_cast<const ushort8v*>(&KL[wid][g * 64 + sub * 16]);
        const ushort8v k1 = *reinterpret_cast<const ushort8v*>(&KL[wid][g * 64 + sub * 16 + 8]);
        float acc = 0.f;
#pragma unroll
        for (int j = 0; j < 8; ++j)
            acc += qf[j] * bf2f(k0[j]) + qf[8 + j] * bf2f(k1[j]);
        s[g] = acc;
    }
    // reduce partial dots across the 4-lane d-group
#pragma unroll
    for (int m = 1; m <= 2; m <<= 1)
#pragma unroll
        for (int g = 0; g < 16; ++g)
            s[g] += __shfl_xor(s[g], m, 64);

    float mx = s[0];
#pragma unroll
    for (int g = 1; g < 16; ++g) mx = fmaxf(mx, s[g]);
    float p[16], denom = 0.f;
#pragma unroll
    for (int g = 0; g < 16; ++g) {
        p[g] = __expf((s[g] - mx) * 0.125f);
        denom += p[g];
    }
    float inv = 1.f / denom;

    float f[16];
#pragma unroll
    for (int j = 0; j < 16; ++j) f[j] = 0.f;
#pragma unroll
    for (int g = 0; g < 16; ++g) {
        float pg = p[g] * inv;
        const ushort8v v0 = *reinterpret_cast<const ushort8v*>(&VL[wid][g * 64 + sub * 16]);
        const ushort8v v1 = *reinterpret_cast<const ushort8v*>(&VL[wid][g * 64 + sub * 16 + 8]);
#pragma unroll
        for (int j = 0; j < 8; ++j) {
            f[j]     += pg * bf2f(v0[j]);
            f[8 + j] += pg * bf2f(v1[j]);
        }
    }
    ushort8v o0, o1;
#pragma unroll
    for (int j = 0; j < 8; ++j) { o0[j] = f2bf(f[j]); o1[j] = f2bf(f[8 + j]); }
    *reinterpret_cast<ushort8v*>(&Fb[base + off])     = o0;
    *reinterpret_cast<ushort8v*>(&Fb[base + off + 8]) = o1;
}

// ---------------------------------------------------------------------------
extern "C" void kernel_launch(void* const* d_in, const int* in_sizes, int n_in,
                              void* d_out, int out_size, void* d_ws, size_t ws_size,
                              hipStream_t stream)
{
    (void)in_sizes; (void)n_in; (void)out_size; (void)ws_size;
    const float* latent = (const float*)d_in[0];
    const float* cond   = (const float*)d_in[1];
    const float* Wq     = (const float*)d_in[2];
    const float* Wk     = (const float*)d_in[3];
    const float* Wv     = (const float*)d_in[4];
    const float* Wout   = (const float*)d_in[5];
    const float* bout   = (const float*)d_in[6];
    float* out = (float*)d_out;

    char* ws = (char*)d_ws;
    const size_t MB = 1ull << 20;
    unsigned short* wqb = (unsigned short*)(ws + 0 * MB);
    unsigned short* wkb = (unsigned short*)(ws + 2 * MB);
    unsigned short* wvb = (unsigned short*)(ws + 4 * MB);
    unsigned short* wob = (unsigned short*)(ws + 6 * MB);
    unsigned short* Qb  = (unsigned short*)(ws + 8 * MB);             // 128 MB, becomes feats
    unsigned short* Kbf = (unsigned short*)(ws + 8 * MB + 128 * MB);  // 128 MB
    unsigned short* Vbf = (unsigned short*)(ws + 8 * MB + 256 * MB);  // 128 MB

    const int n4 = (KDIM * NDIM) / 4;
    f32_to_bf16_k<<<1024, 256, 0, stream>>>(Wq,   wqb, n4);
    f32_to_bf16_k<<<1024, 256, 0, stream>>>(Wk,   wkb, n4);
    f32_to_bf16_k<<<1024, 256, 0, stream>>>(Wv,   wvb, n4);
    f32_to_bf16_k<<<1024, 256, 0, stream>>>(Wout, wob, n4);

    dim3 ggrid(NDIM / 128, NB / 128);  // (8, 512)
    gemm_bt<1, 0><<<ggrid, 256, 0, stream>>>(latent, wqb, nullptr, Qb);
    gemm_bt<1, 0><<<ggrid, 256, 0, stream>>>(cond,   wkb, nullptr, Kbf);
    gemm_bt<1, 0><<<ggrid, 256, 0, stream>>>(cond,   wvb, nullptr, Vbf);

    attn_k<<<NB / 4, 256, 0, stream>>>(Qb, Kbf, Vbf, Qb);

    gemm_bt<0, 1><<<ggrid, 256, 0, stream>>>(Qb, wob, bout, out);
}

// Round 3
// 1361.903 us; speedup vs baseline: 1.0039x; 1.0013x over previous
//
#include <hip/hip_runtime.h>
#include <hip/hip_bf16.h>

// Problem constants
#define NB    65536      // batch rows
#define KDIM  1024       // reduction dim for all projections
#define NDIM  1024       // output dim per projection

typedef float f32x4 __attribute__((ext_vector_type(4)));
typedef short short8 __attribute__((ext_vector_type(8)));
typedef unsigned short ushort8v __attribute__((ext_vector_type(8)));

static __device__ __forceinline__ unsigned short f2bf(float f) {
    union { float f; unsigned u; } v; v.f = f;
    unsigned r = v.u + 0x7FFFu + ((v.u >> 16) & 1u);
    return (unsigned short)(r >> 16);
}
static __device__ __forceinline__ float bf2f(unsigned short h) {
    union { unsigned u; float f; } v; v.u = ((unsigned)h) << 16;
    return v.f;
}

// ---------------------------------------------------------------------------
// fp32 -> bf16 convert (weights), 4 elems/thread
// ---------------------------------------------------------------------------
__global__ __launch_bounds__(256) void f32_to_bf16_k(
    const float* __restrict__ s, unsigned short* __restrict__ d, int n4)
{
    int i = blockIdx.x * 256 + threadIdx.x;
    if (i < n4) {
        float4 v = reinterpret_cast<const float4*>(s)[i];
        ushort4 o;
        o.x = f2bf(v.x); o.y = f2bf(v.y); o.z = f2bf(v.z); o.w = f2bf(v.w);
        reinterpret_cast<ushort4*>(d)[i] = o;
    }
}

// ---------------------------------------------------------------------------
// GEMM: C[M,N] = A[M,K] @ W[N,K]^T (+bias), MFMA 16x16x32 bf16
// 128x128 tile, BK=32, 4 waves (2x2), reg-staged LDS with +8 pad
// A_F32: A is fp32 (convert during staging) else bf16
// OUT_F32: write fp32 with bias, else write bf16
// ---------------------------------------------------------------------------
template<int A_F32, int OUT_F32>
__global__ __launch_bounds__(256) void gemm_bt(
    const void* __restrict__ Aptr, const unsigned short* __restrict__ W,
    const float* __restrict__ bias, void* __restrict__ Cptr)
{
    constexpr int K = KDIM, N = NDIM;
    __shared__ alignas(16) unsigned short As[128][40];
    __shared__ alignas(16) unsigned short Bs[128][40];

    const int t    = threadIdx.x;
    const int lane = t & 63;
    const int wid  = t >> 6;
    const int wr   = wid >> 1;        // wave row (0..1), 64 rows each
    const int wc   = wid & 1;         // wave col (0..1), 64 cols each
    const int bn0  = blockIdx.x * 128;
    const int bm0  = blockIdx.y * 128;
    const int frow = lane & 15;
    const int fk   = (lane >> 4) * 8;

    f32x4 acc[4][4];
#pragma unroll
    for (int mi = 0; mi < 4; ++mi)
#pragma unroll
        for (int ni = 0; ni < 4; ++ni)
            acc[mi][ni] = (f32x4){0.f, 0.f, 0.f, 0.f};

    for (int kk = 0; kk < K; kk += 32) {
        __syncthreads();
        // ---- stage A tile [128 x 32] -> bf16 LDS
        if (A_F32) {
            const float* A = (const float*)Aptr;
#pragma unroll
            for (int it = 0; it < 4; ++it) {
                int row = (t >> 3) + it * 32;
                int col = (t & 7) * 4;
                float4 v = *reinterpret_cast<const float4*>(
                    &A[(size_t)(bm0 + row) * K + kk + col]);
                ushort4 o;
                o.x = f2bf(v.x); o.y = f2bf(v.y); o.z = f2bf(v.z); o.w = f2bf(v.w);
                *reinterpret_cast<ushort4*>(&As[row][col]) = o;
            }
        } else {
            const unsigned short* A = (const unsigned short*)Aptr;
#pragma unroll
            for (int it = 0; it < 2; ++it) {
                int row = (t >> 2) + it * 64;
                int col = (t & 3) * 8;
                ushort8v v = *reinterpret_cast<const ushort8v*>(
                    &A[(size_t)(bm0 + row) * K + kk + col]);
                *reinterpret_cast<ushort8v*>(&As[row][col]) = v;
            }
        }
        // ---- stage B tile: W rows [bn0..bn0+128) x [kk..kk+32), bf16
#pragma unroll
        for (int it = 0; it < 2; ++it) {
            int row = (t >> 2) + it * 64;
            int col = (t & 3) * 8;
            ushort8v v = *reinterpret_cast<const ushort8v*>(
                &W[(size_t)(bn0 + row) * K + kk + col]);
            *reinterpret_cast<ushort8v*>(&Bs[row][col]) = v;
        }
        __syncthreads();

        short8 a[4], b[4];
#pragma unroll
        for (int mi = 0; mi < 4; ++mi)
            a[mi] = *reinterpret_cast<const short8*>(&As[wr * 64 + mi * 16 + frow][fk]);
#pragma unroll
        for (int ni = 0; ni < 4; ++ni)
            b[ni] = *reinterpret_cast<const short8*>(&Bs[wc * 64 + ni * 16 + frow][fk]);
#pragma unroll
        for (int mi = 0; mi < 4; ++mi)
#pragma unroll
            for (int ni = 0; ni < 4; ++ni)
                acc[mi][ni] = __builtin_amdgcn_mfma_f32_16x16x32_bf16(
                    a[mi], b[ni], acc[mi][ni], 0, 0, 0);
    }

    // ---- epilogue: D row = (lane>>4)*4 + r, col = lane&15  [m89-verified]
    const int crow = (lane >> 4) * 4;
    const int ccol = lane & 15;
    if (OUT_F32) {
        float* Cf = (float*)Cptr;
        float bv[4];
#pragma unroll
        for (int ni = 0; ni < 4; ++ni)
            bv[ni] = bias[bn0 + wc * 64 + ni * 16 + ccol];
#pragma unroll
        for (int mi = 0; mi < 4; ++mi)
#pragma unroll
            for (int ni = 0; ni < 4; ++ni) {
                size_t base = (size_t)(bm0 + wr * 64 + mi * 16 + crow) * N
                            + (bn0 + wc * 64 + ni * 16 + ccol);
#pragma unroll
                for (int r = 0; r < 4; ++r)
                    Cf[base + (size_t)r * N] = acc[mi][ni][r] + bv[ni];
            }
    } else {
        unsigned short* Cb = (unsigned short*)Cptr;
#pragma unroll
        for (int mi = 0; mi < 4; ++mi)
#pragma unroll
            for (int ni = 0; ni < 4; ++ni) {
                size_t base = (size_t)(bm0 + wr * 64 + mi * 16 + crow) * N
                            + (bn0 + wc * 64 + ni * 16 + ccol);
#pragma unroll
                for (int r = 0; r < 4; ++r)
                    Cb[base + (size_t)r * N] = f2bf(acc[mi][ni][r]);
            }
    }
}

// ---------------------------------------------------------------------------
// Per-row attention: scores[16,16] = Q K^T * 1/8, softmax, feats = P V.
// 1 wave per row, 4 waves/block. K,V rows staged in LDS.
// lane -> (h = lane>>2, sub = lane&3); lane owns d in [sub*16, sub*16+16).
// feats written over the Q buffer (same rows, read-before-write within wave).
// ---------------------------------------------------------------------------
__global__ __launch_bounds__(256) void attn_k(
    const unsigned short* __restrict__ Qb, const unsigned short* __restrict__ Kb,
    const unsigned short* __restrict__ Vb, unsigned short* __restrict__ Fb)
{
    __shared__ alignas(16) unsigned short KL[4][1024];
    __shared__ alignas(16) unsigned short VL[4][1024];
    const int t = threadIdx.x;
    const int lane = t & 63;
    const int wid = t >> 6;
    const size_t row = (size_t)blockIdx.x * 4 + wid;
    const size_t base = row * 1024;
    const int off = lane * 16;

    // Q chunk for this lane: Q[h][sub*16 .. +16) == elements [lane*16, +16)
    ushort8v q0 = *reinterpret_cast<const ushort8v*>(&Qb[base + off]);
    ushort8v q1 = *reinterpret_cast<const ushort8v*>(&Qb[base + off + 8]);
    float qf[16];
#pragma unroll
    for (int j = 0; j < 8; ++j) { qf[j] = bf2f(q0[j]); qf[8 + j] = bf2f(q1[j]); }

    // stage K,V rows
    *reinterpret_cast<ushort8v*>(&KL[wid][off])     = *reinterpret_cast<const ushort8v*>(&Kb[base + off]);
    *reinterpret_cast<ushort8v*>(&KL[wid][off + 8]) = *reinterpret_cast<const ushort8v*>(&Kb[base + off + 8]);
    *reinterpret_cast<ushort8v*>(&VL[wid][off])     = *reinterpret_cast<const ushort8v*>(&Vb[base + off]);
    *reinterpret_cast<ushort8v*>(&VL[wid][off + 8]) = *reinterpret_cast<const ushort8v*>(&Vb[base + off + 8]);
    __syncthreads();

    const int sub = lane & 3;
    float s[16];
#pragma unroll
    for (int g = 0; g < 16; ++g) {
        const ushort8v k0 = *reinterpret_cast<const ushort8v*>(&KL[wid][g * 64 + sub * 16]);
        const ushort8v k1 = *reinterpret_cast<const ushort8v*>(&KL[wid][g * 64 + sub * 16 + 8]);
        float acc = 0.f;
#pragma unroll
        for (int j = 0; j < 8; ++j)
            acc += qf[j] * bf2f(k0[j]) + qf[8 + j] * bf2f(k1[j]);
        s[g] = acc;
    }
    // reduce partial dots across the 4-lane d-group
#pragma unroll
    for (int m = 1; m <= 2; m <<= 1)
#pragma unroll
        for (int g = 0; g < 16; ++g)
            s[g] += __shfl_xor(s[g], m, 64);

    float mx = s[0];
#pragma unroll
    for (int g = 1; g < 16; ++g) mx = fmaxf(mx, s[g]);
    float p[16], denom = 0.f;
#pragma unroll
    for (int g = 0; g < 16; ++g) {
        p[g] = __expf((s[g] - mx) * 0.125f);
        denom += p[g];
    }
    float inv = 1.f / denom;

    float f[16];
#pragma unroll
    for (int j = 0; j < 16; ++j) f[j] = 0.f;
#pragma unroll
    for (int g = 0; g < 16; ++g) {
        float pg = p[g] * inv;
        const ushort8v v0 = *reinterpret_cast<const ushort8v*>(&VL[wid][g * 64 + sub * 16]);
        const ushort8v v1 = *reinterpret_cast<const ushort8v*>(&VL[wid][g * 64 + sub * 16 + 8]);
#pragma unroll
        for (int j = 0; j < 8; ++j) {
            f[j]     += pg * bf2f(v0[j]);
            f[8 + j] += pg * bf2f(v1[j]);
        }
    }
    ushort8v o0, o1;
#pragma unroll
    for (int j = 0; j < 8; ++j) { o0[j] = f2bf(f[j]); o1[j] = f2bf(f[8 + j]); }
    *reinterpret_cast<ushort8v*>(&Fb[base + off])     = o0;
    *reinterpret_cast<ushort8v*>(&Fb[base + off + 8]) = o1;
}

// ---------------------------------------------------------------------------
extern "C" void kernel_launch(void* const* d_in, const int* in_sizes, int n_in,
                              void* d_out, int out_size, void* d_ws, size_t ws_size,
                              hipStream_t stream)
{
    (void)in_sizes; (void)n_in; (void)out_size; (void)ws_size;
    const float* latent = (const float*)d_in[0];
    const float* cond   = (const float*)d_in[1];
    const float* Wq     = (const float*)d_in[2];
    const float* Wk     = (const float*)d_in[3];
    const float* Wv     = (const float*)d_in[4];
    const float* Wout   = (const float*)d_in[5];
    const float* bout   = (const float*)d_in[6];
    float* out = (float*)d_out;

    char* ws = (char*)d_ws;
    const size_t MB = 1ull << 20;
    unsigned short* wqb = (unsigned short*)(ws + 0 * MB);
    unsigned short* wkb = (unsigned short*)(ws + 2 * MB);
    unsigned short* wvb = (unsigned short*)(ws + 4 * MB);
    unsigned short* wob = (unsigned short*)(ws + 6 * MB);
    unsigned short* Qb  = (unsigned short*)(ws + 8 * MB);             // 128 MB, becomes feats
    unsigned short* Kbf = (unsigned short*)(ws + 8 * MB + 128 * MB);  // 128 MB
    unsigned short* Vbf = (unsigned short*)(ws + 8 * MB + 256 * MB);  // 128 MB

    const int n4 = (KDIM * NDIM) / 4;
    f32_to_bf16_k<<<1024, 256, 0, stream>>>(Wq,   wqb, n4);
    f32_to_bf16_k<<<1024, 256, 0, stream>>>(Wk,   wkb, n4);
    f32_to_bf16_k<<<1024, 256, 0, stream>>>(Wv,   wvb, n4);
    f32_to_bf16_k<<<1024, 256, 0, stream>>>(Wout, wob, n4);

    dim3 ggrid(NDIM / 128, NB / 128);  // (8, 512)
    gemm_bt<1, 0><<<ggrid, 256, 0, stream>>>(latent, wqb, nullptr, Qb);
    gemm_bt<1, 0><<<ggrid, 256, 0, stream>>>(cond,   wkb, nullptr, Kbf);
    gemm_bt<1, 0><<<ggrid, 256, 0, stream>>>(cond,   wvb, nullptr, Vbf);

    attn_k<<<NB / 4, 256, 0, stream>>>(Qb, Kbf, Vbf, Qb);

    gemm_bt<0, 1><<<ggrid, 256, 0, stream>>>(Qb, wob, bout, out);
}

// Round 4
// 1073.306 us; speedup vs baseline: 1.2738x; 1.2689x over previous
//
#include <hip/hip_runtime.h>
#include <hip/hip_bf16.h>

// Problem constants
#define NB    65536      // batch rows
#define KDIM  1024       // reduction dim for all projections
#define NDIM  1024       // output dim per projection

typedef float f32x4 __attribute__((ext_vector_type(4)));
typedef short short8 __attribute__((ext_vector_type(8)));
typedef unsigned short ushort8v __attribute__((ext_vector_type(8)));

static __device__ __forceinline__ unsigned short f2bf(float f) {
    union { float f; unsigned u; } v; v.f = f;
    unsigned r = v.u + 0x7FFFu + ((v.u >> 16) & 1u);
    return (unsigned short)(r >> 16);
}
static __device__ __forceinline__ float bf2f(unsigned short h) {
    union { unsigned u; float f; } v; v.u = ((unsigned)h) << 16;
    return v.f;
}

// async global->LDS, 16B per lane. LDS dest is wave-uniform base + lane*16.
static __device__ __forceinline__ void gload16(const unsigned short* g, unsigned short* l) {
    __builtin_amdgcn_global_load_lds(
        (const __attribute__((address_space(1))) unsigned int*)g,
        (__attribute__((address_space(3))) unsigned int*)l, 16, 0, 0);
}

// ---------------------------------------------------------------------------
// fp32 -> bf16 convert, grid-stride, 4 elems/thread/iter
// ---------------------------------------------------------------------------
__global__ __launch_bounds__(256) void f32_to_bf16_k(
    const float* __restrict__ s, unsigned short* __restrict__ d, int n4)
{
    const int stride = gridDim.x * 256;
    for (int i = blockIdx.x * 256 + threadIdx.x; i < n4; i += stride) {
        float4 v = reinterpret_cast<const float4*>(s)[i];
        ushort4 o;
        o.x = f2bf(v.x); o.y = f2bf(v.y); o.z = f2bf(v.z); o.w = f2bf(v.w);
        reinterpret_cast<ushort4*>(d)[i] = o;
    }
}

// ---------------------------------------------------------------------------
// m97-structure GEMM: C[M,N] = A[M,K] @ W[N,K]^T (+bias)
// bf16 A, 128x128 tile, BK=32, 4 waves (2x2), linear LDS, global_load_lds x16,
// XCD-chunked blockIdx swizzle (1-D grid, nwg % 8 == 0).
// ---------------------------------------------------------------------------
template<int OUT_F32>
__global__ __launch_bounds__(256) void gemm_lds(
    const unsigned short* __restrict__ A, const unsigned short* __restrict__ W,
    const float* __restrict__ bias, void* __restrict__ Cptr)
{
    constexpr int K = KDIM, N = NDIM;
    constexpr int GN = NDIM / 128;           // 8 col-tiles
    __shared__ alignas(16) unsigned short As[128 * 32];
    __shared__ alignas(16) unsigned short Bs[128 * 32];

    // XCD swizzle: hw round-robins blockIdx across 8 XCDs; give each XCD a
    // contiguous chunk so the 8 blocks sharing an A-panel stay on one L2.
    const int nwg  = gridDim.x;
    const int cpx  = nwg >> 3;               // chunks per XCD (nwg % 8 == 0)
    const int orig = blockIdx.x;
    const int wgid = (orig & 7) * cpx + (orig >> 3);
    const int bn0  = (wgid & (GN - 1)) * 128;   // col tile fastest within chunk
    const int bm0  = (wgid / GN) * 128;

    const int t    = threadIdx.x;
    const int lane = t & 63;
    const int wid  = t >> 6;
    const int wr   = wid >> 1;               // wave row (0..1)
    const int wc   = wid & 1;                // wave col (0..1)
    const int frow = lane & 15;
    const int fk   = (lane >> 4) * 8;

    // staging geometry: wave `wid` owns rows [wid*32, wid*32+32) of each tile;
    // 2 gload16 per tile per wave, each covering 16 rows x 32 cols (1024 B).
    const int srow = wid * 32 + (lane >> 2); // per-lane source row (instr j adds 16)
    const int scol = (lane & 3) * 8;
    const unsigned short* gaBase = A + (size_t)(bm0 + srow) * K + scol;
    const unsigned short* gbBase = W + (size_t)(bn0 + srow) * K + scol;
    unsigned short* la = As + (wid * 32) * 32;   // wave-uniform LDS base
    unsigned short* lb = Bs + (wid * 32) * 32;

    f32x4 acc[4][4];
#pragma unroll
    for (int mi = 0; mi < 4; ++mi)
#pragma unroll
        for (int ni = 0; ni < 4; ++ni)
            acc[mi][ni] = (f32x4){0.f, 0.f, 0.f, 0.f};

    for (int kk = 0; kk < K; kk += 32) {
        gload16(gaBase + kk,            la);
        gload16(gaBase + kk + 16 * K,   la + 16 * 32);
        gload16(gbBase + kk,            lb);
        gload16(gbBase + kk + 16 * K,   lb + 16 * 32);
        __syncthreads();                 // drains vmcnt(0): tile visible

        short8 a[4], b[4];
#pragma unroll
        for (int mi = 0; mi < 4; ++mi)
            a[mi] = *reinterpret_cast<const short8*>(
                As + (wr * 64 + mi * 16 + frow) * 32 + fk);
#pragma unroll
        for (int ni = 0; ni < 4; ++ni)
            b[ni] = *reinterpret_cast<const short8*>(
                Bs + (wc * 64 + ni * 16 + frow) * 32 + fk);
#pragma unroll
        for (int mi = 0; mi < 4; ++mi)
#pragma unroll
            for (int ni = 0; ni < 4; ++ni)
                acc[mi][ni] = __builtin_amdgcn_mfma_f32_16x16x32_bf16(
                    a[mi], b[ni], acc[mi][ni], 0, 0, 0);
        __syncthreads();                 // all reads done before next stage
    }

    // epilogue: D row = (lane>>4)*4 + r, col = lane&15  [m89-verified]
    const int crow = (lane >> 4) * 4;
    const int ccol = lane & 15;
    if (OUT_F32) {
        float* Cf = (float*)Cptr;
        float bv[4];
#pragma unroll
        for (int ni = 0; ni < 4; ++ni)
            bv[ni] = bias[bn0 + wc * 64 + ni * 16 + ccol];
#pragma unroll
        for (int mi = 0; mi < 4; ++mi)
#pragma unroll
            for (int ni = 0; ni < 4; ++ni) {
                size_t base = (size_t)(bm0 + wr * 64 + mi * 16 + crow) * N
                            + (bn0 + wc * 64 + ni * 16 + ccol);
#pragma unroll
                for (int r = 0; r < 4; ++r)
                    Cf[base + (size_t)r * N] = acc[mi][ni][r] + bv[ni];
            }
    } else {
        unsigned short* Cb = (unsigned short*)Cptr;
#pragma unroll
        for (int mi = 0; mi < 4; ++mi)
#pragma unroll
            for (int ni = 0; ni < 4; ++ni) {
                size_t base = (size_t)(bm0 + wr * 64 + mi * 16 + crow) * N
                            + (bn0 + wc * 64 + ni * 16 + ccol);
#pragma unroll
                for (int r = 0; r < 4; ++r)
                    Cb[base + (size_t)r * N] = f2bf(acc[mi][ni][r]);
            }
    }
}

// ---------------------------------------------------------------------------
// Fallback GEMM (fp32 A, reg-staged) — used only if ws_size too small for the
// bf16 pre-convert buffers. Verified-passing round-3 kernel.
// ---------------------------------------------------------------------------
__global__ __launch_bounds__(256) void gemm_bt_f32a(
    const float* __restrict__ A, const unsigned short* __restrict__ W,
    unsigned short* __restrict__ Cb)
{
    constexpr int K = KDIM, N = NDIM;
    __shared__ alignas(16) unsigned short As[128][40];
    __shared__ alignas(16) unsigned short Bs[128][40];

    const int t    = threadIdx.x;
    const int lane = t & 63;
    const int wid  = t >> 6;
    const int wr   = wid >> 1;
    const int wc   = wid & 1;
    const int bn0  = blockIdx.x * 128;
    const int bm0  = blockIdx.y * 128;
    const int frow = lane & 15;
    const int fk   = (lane >> 4) * 8;

    f32x4 acc[4][4];
#pragma unroll
    for (int mi = 0; mi < 4; ++mi)
#pragma unroll
        for (int ni = 0; ni < 4; ++ni)
            acc[mi][ni] = (f32x4){0.f, 0.f, 0.f, 0.f};

    for (int kk = 0; kk < K; kk += 32) {
        __syncthreads();
#pragma unroll
        for (int it = 0; it < 4; ++it) {
            int row = (t >> 3) + it * 32;
            int col = (t & 7) * 4;
            float4 v = *reinterpret_cast<const float4*>(
                &A[(size_t)(bm0 + row) * K + kk + col]);
            ushort4 o;
            o.x = f2bf(v.x); o.y = f2bf(v.y); o.z = f2bf(v.z); o.w = f2bf(v.w);
            *reinterpret_cast<ushort4*>(&As[row][col]) = o;
        }
#pragma unroll
        for (int it = 0; it < 2; ++it) {
            int row = (t >> 2) + it * 64;
            int col = (t & 3) * 8;
            ushort8v v = *reinterpret_cast<const ushort8v*>(
                &W[(size_t)(bn0 + row) * K + kk + col]);
            *reinterpret_cast<ushort8v*>(&Bs[row][col]) = v;
        }
        __syncthreads();

        short8 a[4], b[4];
#pragma unroll
        for (int mi = 0; mi < 4; ++mi)
            a[mi] = *reinterpret_cast<const short8*>(&As[wr * 64 + mi * 16 + frow][fk]);
#pragma unroll
        for (int ni = 0; ni < 4; ++ni)
            b[ni] = *reinterpret_cast<const short8*>(&Bs[wc * 64 + ni * 16 + frow][fk]);
#pragma unroll
        for (int mi = 0; mi < 4; ++mi)
#pragma unroll
            for (int ni = 0; ni < 4; ++ni)
                acc[mi][ni] = __builtin_amdgcn_mfma_f32_16x16x32_bf16(
                    a[mi], b[ni], acc[mi][ni], 0, 0, 0);
    }

    const int crow = (lane >> 4) * 4;
    const int ccol = lane & 15;
#pragma unroll
    for (int mi = 0; mi < 4; ++mi)
#pragma unroll
        for (int ni = 0; ni < 4; ++ni) {
            size_t base = (size_t)(bm0 + wr * 64 + mi * 16 + crow) * N
                        + (bn0 + wc * 64 + ni * 16 + ccol);
#pragma unroll
            for (int r = 0; r < 4; ++r)
                Cb[base + (size_t)r * N] = f2bf(acc[mi][ni][r]);
        }
}

// ---------------------------------------------------------------------------
// Per-row attention (unchanged, verified): 1 wave/row, 4 waves/block.
// ---------------------------------------------------------------------------
__global__ __launch_bounds__(256) void attn_k(
    const unsigned short* __restrict__ Qb, const unsigned short* __restrict__ Kb,
    const unsigned short* __restrict__ Vb, unsigned short* __restrict__ Fb)
{
    __shared__ alignas(16) unsigned short KL[4][1024];
    __shared__ alignas(16) unsigned short VL[4][1024];
    const int t = threadIdx.x;
    const int lane = t & 63;
    const int wid = t >> 6;
    const size_t row = (size_t)blockIdx.x * 4 + wid;
    const size_t base = row * 1024;
    const int off = lane * 16;

    ushort8v q0 = *reinterpret_cast<const ushort8v*>(&Qb[base + off]);
    ushort8v q1 = *reinterpret_cast<const ushort8v*>(&Qb[base + off + 8]);
    float qf[16];
#pragma unroll
    for (int j = 0; j < 8; ++j) { qf[j] = bf2f(q0[j]); qf[8 + j] = bf2f(q1[j]); }

    *reinterpret_cast<ushort8v*>(&KL[wid][off])     = *reinterpret_cast<const ushort8v*>(&Kb[base + off]);
    *reinterpret_cast<ushort8v*>(&KL[wid][off + 8]) = *reinterpret_cast<const ushort8v*>(&Kb[base + off + 8]);
    *reinterpret_cast<ushort8v*>(&VL[wid][off])     = *reinterpret_cast<const ushort8v*>(&Vb[base + off]);
    *reinterpret_cast<ushort8v*>(&VL[wid][off + 8]) = *reinterpret_cast<const ushort8v*>(&Vb[base + off + 8]);
    __syncthreads();

    const int sub = lane & 3;
    float s[16];
#pragma unroll
    for (int g = 0; g < 16; ++g) {
        const ushort8v k0 = *reinterpret_cast<const ushort8v*>(&KL[wid][g * 64 + sub * 16]);
        const ushort8v k1 = *reinterpret_cast<const ushort8v*>(&KL[wid][g * 64 + sub * 16 + 8]);
        float acc = 0.f;
#pragma unroll
        for (int j = 0; j < 8; ++j)
            acc += qf[j] * bf2f(k0[j]) + qf[8 + j] * bf2f(k1[j]);
        s[g] = acc;
    }
#pragma unroll
    for (int m = 1; m <= 2; m <<= 1)
#pragma unroll
        for (int g = 0; g < 16; ++g)
            s[g] += __shfl_xor(s[g], m, 64);

    float mx = s[0];
#pragma unroll
    for (int g = 1; g < 16; ++g) mx = fmaxf(mx, s[g]);
    float p[16], denom = 0.f;
#pragma unroll
    for (int g = 0; g < 16; ++g) {
        p[g] = __expf((s[g] - mx) * 0.125f);
        denom += p[g];
    }
    float inv = 1.f / denom;

    float f[16];
#pragma unroll
    for (int j = 0; j < 16; ++j) f[j] = 0.f;
#pragma unroll
    for (int g = 0; g < 16; ++g) {
        float pg = p[g] * inv;
        const ushort8v v0 = *reinterpret_cast<const ushort8v*>(&VL[wid][g * 64 + sub * 16]);
        const ushort8v v1 = *reinterpret_cast<const ushort8v*>(&VL[wid][g * 64 + sub * 16 + 8]);
#pragma unroll
        for (int j = 0; j < 8; ++j) {
            f[j]     += pg * bf2f(v0[j]);
            f[8 + j] += pg * bf2f(v1[j]);
        }
    }
    ushort8v o0, o1;
#pragma unroll
    for (int j = 0; j < 8; ++j) { o0[j] = f2bf(f[j]); o1[j] = f2bf(f[8 + j]); }
    *reinterpret_cast<ushort8v*>(&Fb[base + off])     = o0;
    *reinterpret_cast<ushort8v*>(&Fb[base + off + 8]) = o1;
}

// ---------------------------------------------------------------------------
extern "C" void kernel_launch(void* const* d_in, const int* in_sizes, int n_in,
                              void* d_out, int out_size, void* d_ws, size_t ws_size,
                              hipStream_t stream)
{
    (void)in_sizes; (void)n_in; (void)out_size;
    const float* latent = (const float*)d_in[0];
    const float* cond   = (const float*)d_in[1];
    const float* Wq     = (const float*)d_in[2];
    const float* Wk     = (const float*)d_in[3];
    const float* Wv     = (const float*)d_in[4];
    const float* Wout   = (const float*)d_in[5];
    const float* bout   = (const float*)d_in[6];
    float* out = (float*)d_out;

    char* ws = (char*)d_ws;
    const size_t MB = 1ull << 20;
    unsigned short* wqb = (unsigned short*)(ws + 0 * MB);
    unsigned short* wkb = (unsigned short*)(ws + 2 * MB);
    unsigned short* wvb = (unsigned short*)(ws + 4 * MB);
    unsigned short* wob = (unsigned short*)(ws + 6 * MB);
    unsigned short* Qb  = (unsigned short*)(ws + 8 * MB);              // 128 MB, becomes feats
    unsigned short* Kbf = (unsigned short*)(ws + 8 * MB + 128 * MB);   // 128 MB
    unsigned short* Vbf = (unsigned short*)(ws + 8 * MB + 256 * MB);   // 128 MB
    unsigned short* Lb  = (unsigned short*)(ws + 8 * MB + 384 * MB);   // 128 MB latent bf16
    unsigned short* Cb  = (unsigned short*)(ws + 8 * MB + 512 * MB);   // 128 MB cond bf16
    const size_t need = 8 * MB + 5 * 128 * MB;                         // 648 MB

    const int wn4 = (KDIM * NDIM) / 4;
    f32_to_bf16_k<<<1024, 256, 0, stream>>>(Wq,   wqb, wn4);
    f32_to_bf16_k<<<1024, 256, 0, stream>>>(Wk,   wkb, wn4);
    f32_to_bf16_k<<<1024, 256, 0, stream>>>(Wv,   wvb, wn4);
    f32_to_bf16_k<<<1024, 256, 0, stream>>>(Wout, wob, wn4);

    const int nblk = (NDIM / 128) * (NB / 128);   // 4096, 1-D swizzled grid

    if (ws_size >= need) {
        const int an4 = (NB * KDIM) / 4;          // 16M float4 groups
        f32_to_bf16_k<<<4096, 256, 0, stream>>>(latent, Lb, an4);
        f32_to_bf16_k<<<4096, 256, 0, stream>>>(cond,   Cb, an4);
        gemm_lds<0><<<nblk, 256, 0, stream>>>(Lb, wqb, nullptr, Qb);
        gemm_lds<0><<<nblk, 256, 0, stream>>>(Cb, wkb, nullptr, Kbf);
        gemm_lds<0><<<nblk, 256, 0, stream>>>(Cb, wvb, nullptr, Vbf);
    } else {
        dim3 ggrid(NDIM / 128, NB / 128);
        gemm_bt_f32a<<<ggrid, 256, 0, stream>>>(latent, wqb, Qb);
        gemm_bt_f32a<<<ggrid, 256, 0, stream>>>(cond,   wkb, Kbf);
        gemm_bt_f32a<<<ggrid, 256, 0, stream>>>(cond,   wvb, Vbf);
    }

    attn_k<<<NB / 4, 256, 0, stream>>>(Qb, Kbf, Vbf, Qb);

    gemm_lds<1><<<nblk, 256, 0, stream>>>(Qb, wob, bout, out);
}

// Round 5
// 1008.968 us; speedup vs baseline: 1.3550x; 1.0638x over previous
//
#include <hip/hip_runtime.h>
#include <hip/hip_bf16.h>

// Problem constants
#define NB    65536      // batch rows
#define KDIM  1024       // reduction dim for all projections
#define NDIM  1024       // output dim per projection

// 256x256 8-phase GEMM geometry
#define BM 256
#define BN 256
#define BK 64
#define NT (KDIM / BK)   // 16 K-tile groups

typedef float f32x4 __attribute__((ext_vector_type(4)));
typedef short short8 __attribute__((ext_vector_type(8)));
typedef unsigned short ushort8v __attribute__((ext_vector_type(8)));

static __device__ __forceinline__ unsigned short f2bf(float f) {
    union { float f; unsigned u; } v; v.f = f;
    unsigned r = v.u + 0x7FFFu + ((v.u >> 16) & 1u);
    return (unsigned short)(r >> 16);
}
static __device__ __forceinline__ float bf2f(unsigned short h) {
    union { unsigned u; float f; } v; v.u = ((unsigned)h) << 16;
    return v.f;
}

// async global->LDS, 16B per lane. LDS dest = wave-uniform base + lane*16.
static __device__ __forceinline__ void gload16(const unsigned short* g, unsigned short* l) {
    __builtin_amdgcn_global_load_lds(
        (const __attribute__((address_space(1))) unsigned int*)g,
        (__attribute__((address_space(3))) unsigned int*)l, 16, 0, 0);
}

// ---------------------------------------------------------------------------
// fp32 -> bf16 convert, grid-stride, 4 elems/thread/iter
// ---------------------------------------------------------------------------
__global__ __launch_bounds__(256) void f32_to_bf16_k(
    const float* __restrict__ s, unsigned short* __restrict__ d, int n4)
{
    const int stride = gridDim.x * 256;
    for (int i = blockIdx.x * 256 + threadIdx.x; i < n4; i += stride) {
        float4 v = reinterpret_cast<const float4*>(s)[i];
        ushort4 o;
        o.x = f2bf(v.x); o.y = f2bf(v.y); o.z = f2bf(v.z); o.w = f2bf(v.w);
        reinterpret_cast<ushort4*>(d)[i] = o;
    }
}

// ---------------------------------------------------------------------------
// 256x256 8-phase GEMM: C[M,N] = A[M,K] @ W[N,K]^T (+bias)
// 512 threads = 8 waves (2 Mwaves x 4 Nwaves); per-wave output 128x64.
// LDS: 2 K-tile buffers x (A 32KB + B 32KB) = 128 KB, FRAGMENT-ORDERED:
//   1KB block (f, ks) holds, at lane*16B, exactly the MFMA fragment slice
//   A[f*16 + (lane&15)][kt*64 + ks*32 + (lane>>4)*8 ..+8). Staged by
//   per-lane pre-swizzled global addresses + linear gload_lds dest (m173
//   pattern) -> every ds_read_b128 is base + lane*16 = conflict-free.
// Pipeline: per K-tile group, 4 phases (quadrant = ks x n-half), each:
//   {12 or 4|10 ds_reads; 2 gload_lds/wave; vmcnt(8); barrier; lgkmcnt(0);
//    setprio(1); 16 MFMA; setprio(0); barrier}
// vmcnt(8) = 4 half-tile chunks in flight; chunk staged >=4 phases before
// its first read, and every LDS overwrite is issued >=1 barrier after the
// last read of that region completes (race-free by barrier ordering).
// Staging schedule (group t): p1:(t+1).A-ks1  p2:(t+1).B-ks1
//                             p3:(t+2).A-ks0  p4:(t+2).B-ks0
// ---------------------------------------------------------------------------
template<int OUT_F32>
__global__ __launch_bounds__(512, 2) void gemm256(
    const unsigned short* __restrict__ Ap, const unsigned short* __restrict__ Wp,
    const float* __restrict__ bias, void* __restrict__ Cptr)
{
    constexpr int N = NDIM;
    constexpr int GN = NDIM / BN;            // 4 col tiles
    __shared__ alignas(16) unsigned short lds[2][2][32][512];  // [buf][A|B][blk=f*2+ks][1KB]

    const int t    = threadIdx.x;
    const int lane = t & 63;
    const int wid  = t >> 6;                 // 0..7
    const int wm   = wid >> 2;               // 0..1  (128 rows each)
    const int wn   = wid & 3;                // 0..3  (64 cols each)

    // XCD-chunked swizzle (nwg = 1024, % 8 == 0)
    const int nwg  = gridDim.x;
    const int cpx  = nwg >> 3;
    const int orig = blockIdx.x;
    const int wgid = (orig & 7) * cpx + (orig >> 3);
    const int bn0  = (wgid & (GN - 1)) * BN;
    const int bm0  = (wgid / GN) * BM;

    // per-lane fragment offset within a block's 16-row x 32-col source region
    const size_t aoff = (size_t)(lane & 15) * KDIM + (lane >> 4) * 8;

#define LDA_(BUF, MI, KS) \
    (*reinterpret_cast<const short8*>(&lds[BUF][0][(wm * 8 + (MI)) * 2 + (KS)][lane * 8]))
#define LDB_(BUF, NI, KS) \
    (*reinterpret_cast<const short8*>(&lds[BUF][1][(wn * 4 + (NI)) * 2 + (KS)][lane * 8]))

    // stage one 16KB chunk (tile TAU, A|B, k-half KS) into buffer slot SLOT:
    // 16 blocks, 2 per wave (f = wid*2 + j), 1KB each.
#define STAGE_(TAU, SLOT, AB, KS) do {                                          \
        int _tc = (TAU) < NT ? (TAU) : NT - 1;  /* tail clamp: keep vmcnt cadence */ \
        const unsigned short* _b = (AB) ? Wp : Ap;                              \
        int _r0 = (AB) ? bn0 : bm0;                                             \
        _Pragma("unroll")                                                       \
        for (int _j = 0; _j < 2; ++_j) {                                        \
            int _f = wid * 2 + _j;                                              \
            gload16(_b + (size_t)(_r0 + _f * 16) * KDIM + _tc * BK + (KS) * 32 + aoff, \
                    &lds[SLOT][AB][_f * 2 + (KS)][0]);                          \
        }                                                                       \
    } while (0)

#define PHASE_SYNC() do {                                                       \
        asm volatile("s_waitcnt vmcnt(8)" ::: "memory");                        \
        __builtin_amdgcn_s_barrier();                                           \
        asm volatile("s_waitcnt lgkmcnt(0)" ::: "memory");                      \
        __builtin_amdgcn_sched_barrier(0);                                      \
    } while (0)

#define MFMA_LO() do { _Pragma("unroll")                                        \
    for (int mi = 0; mi < 8; ++mi) {                                            \
        acc[mi][0] = __builtin_amdgcn_mfma_f32_16x16x32_bf16(af[mi], bq0, acc[mi][0], 0, 0, 0); \
        acc[mi][1] = __builtin_amdgcn_mfma_f32_16x16x32_bf16(af[mi], bq1, acc[mi][1], 0, 0, 0); \
    } } while (0)
#define MFMA_HI() do { _Pragma("unroll")                                        \
    for (int mi = 0; mi < 8; ++mi) {                                            \
        acc[mi][2] = __builtin_amdgcn_mfma_f32_16x16x32_bf16(af[mi], bq2, acc[mi][2], 0, 0, 0); \
        acc[mi][3] = __builtin_amdgcn_mfma_f32_16x16x32_bf16(af[mi], bq3, acc[mi][3], 0, 0, 0); \
    } } while (0)

#define GROUP_(BUF, OBUF, TT) do {                                              \
        /* phase 1: (ks0, n-lo) */                                              \
        _Pragma("unroll")                                                       \
        for (int mi = 0; mi < 8; ++mi) af[mi] = LDA_(BUF, mi, 0);               \
        bq0 = LDB_(BUF, 0, 0); bq1 = LDB_(BUF, 1, 0);                           \
        STAGE_((TT) + 1, OBUF, 0, 1);                                           \
        PHASE_SYNC();                                                           \
        __builtin_amdgcn_s_setprio(1); MFMA_LO(); __builtin_amdgcn_s_setprio(0);\
        __builtin_amdgcn_s_barrier();                                           \
        /* phase 2: (ks0, n-hi) */                                              \
        bq2 = LDB_(BUF, 2, 0); bq3 = LDB_(BUF, 3, 0);                           \
        STAGE_((TT) + 1, OBUF, 1, 1);                                           \
        PHASE_SYNC();                                                           \
        __builtin_amdgcn_s_setprio(1); MFMA_HI(); __builtin_amdgcn_s_setprio(0);\
        __builtin_amdgcn_s_barrier();                                           \
        /* phase 3: (ks1, n-lo) */                                              \
        _Pragma("unroll")                                                       \
        for (int mi = 0; mi < 8; ++mi) af[mi] = LDA_(BUF, mi, 1);               \
        bq0 = LDB_(BUF, 0, 1); bq1 = LDB_(BUF, 1, 1);                           \
        STAGE_((TT) + 2, BUF, 0, 0);                                            \
        PHASE_SYNC();                                                           \
        __builtin_amdgcn_s_setprio(1); MFMA_LO(); __builtin_amdgcn_s_setprio(0);\
        __builtin_amdgcn_s_barrier();                                           \
        /* phase 4: (ks1, n-hi) */                                              \
        bq2 = LDB_(BUF, 2, 1); bq3 = LDB_(BUF, 3, 1);                           \
        STAGE_((TT) + 2, BUF, 1, 0);                                            \
        PHASE_SYNC();                                                           \
        __builtin_amdgcn_s_setprio(1); MFMA_HI(); __builtin_amdgcn_s_setprio(0);\
        __builtin_amdgcn_s_barrier();                                           \
    } while (0)

    f32x4 acc[8][4];
#pragma unroll
    for (int mi = 0; mi < 8; ++mi)
#pragma unroll
        for (int ni = 0; ni < 4; ++ni)
            acc[mi][ni] = (f32x4){0.f, 0.f, 0.f, 0.f};

    short8 af[8], bq0, bq1, bq2, bq3;

    // prologue: tile0 fully + tile1 k-half0 (12 loads/wave); retire tile0-ks0
    STAGE_(0, 0, 0, 0); STAGE_(0, 0, 1, 0);
    STAGE_(0, 0, 0, 1); STAGE_(0, 0, 1, 1);
    STAGE_(1, 1, 0, 0); STAGE_(1, 1, 1, 0);
    asm volatile("s_waitcnt vmcnt(8)" ::: "memory");
    __builtin_amdgcn_s_barrier();

#pragma unroll 1
    for (int tt = 0; tt < NT; tt += 2) {
        GROUP_(0, 1, tt);
        GROUP_(1, 0, tt + 1);
    }

    // epilogue: D row = (lane>>4)*4 + r, col = lane&15  [m89-verified]
    const int crow = (lane >> 4) * 4;
    const int ccol = lane & 15;
    if (OUT_F32) {
        float* Cf = (float*)Cptr;
        float bv[4];
#pragma unroll
        for (int ni = 0; ni < 4; ++ni)
            bv[ni] = bias[bn0 + wn * 64 + ni * 16 + ccol];
#pragma unroll
        for (int mi = 0; mi < 8; ++mi)
#pragma unroll
            for (int ni = 0; ni < 4; ++ni) {
                size_t base = (size_t)(bm0 + wm * 128 + mi * 16 + crow) * N
                            + (bn0 + wn * 64 + ni * 16 + ccol);
#pragma unroll
                for (int r = 0; r < 4; ++r)
                    Cf[base + (size_t)r * N] = acc[mi][ni][r] + bv[ni];
            }
    } else {
        unsigned short* Cb = (unsigned short*)Cptr;
#pragma unroll
        for (int mi = 0; mi < 8; ++mi)
#pragma unroll
            for (int ni = 0; ni < 4; ++ni) {
                size_t base = (size_t)(bm0 + wm * 128 + mi * 16 + crow) * N
                            + (bn0 + wn * 64 + ni * 16 + ccol);
#pragma unroll
                for (int r = 0; r < 4; ++r)
                    Cb[base + (size_t)r * N] = f2bf(acc[mi][ni][r]);
            }
    }
#undef LDA_
#undef LDB_
#undef STAGE_
#undef PHASE_SYNC
#undef MFMA_LO
#undef MFMA_HI
#undef GROUP_
}

// ---------------------------------------------------------------------------
// Per-row attention (unchanged, verified): 1 wave/row, 4 waves/block.
// ---------------------------------------------------------------------------
__global__ __launch_bounds__(256) void attn_k(
    const unsigned short* __restrict__ Qb, const unsigned short* __restrict__ Kb,
    const unsigned short* __restrict__ Vb, unsigned short* __restrict__ Fb)
{
    __shared__ alignas(16) unsigned short KL[4][1024];
    __shared__ alignas(16) unsigned short VL[4][1024];
    const int t = threadIdx.x;
    const int lane = t & 63;
    const int wid = t >> 6;
    const size_t row = (size_t)blockIdx.x * 4 + wid;
    const size_t base = row * 1024;
    const int off = lane * 16;

    ushort8v q0 = *reinterpret_cast<const ushort8v*>(&Qb[base + off]);
    ushort8v q1 = *reinterpret_cast<const ushort8v*>(&Qb[base + off + 8]);
    float qf[16];
#pragma unroll
    for (int j = 0; j < 8; ++j) { qf[j] = bf2f(q0[j]); qf[8 + j] = bf2f(q1[j]); }

    *reinterpret_cast<ushort8v*>(&KL[wid][off])     = *reinterpret_cast<const ushort8v*>(&Kb[base + off]);
    *reinterpret_cast<ushort8v*>(&KL[wid][off + 8]) = *reinterpret_cast<const ushort8v*>(&Kb[base + off + 8]);
    *reinterpret_cast<ushort8v*>(&VL[wid][off])     = *reinterpret_cast<const ushort8v*>(&Vb[base + off]);
    *reinterpret_cast<ushort8v*>(&VL[wid][off + 8]) = *reinterpret_cast<const ushort8v*>(&Vb[base + off + 8]);
    __syncthreads();

    const int sub = lane & 3;
    float s[16];
#pragma unroll
    for (int g = 0; g < 16; ++g) {
        const ushort8v k0 = *reinterpret_cast<const ushort8v*>(&KL[wid][g * 64 + sub * 16]);
        const ushort8v k1 = *reinterpret_cast<const ushort8v*>(&KL[wid][g * 64 + sub * 16 + 8]);
        float acc = 0.f;
#pragma unroll
        for (int j = 0; j < 8; ++j)
            acc += qf[j] * bf2f(k0[j]) + qf[8 + j] * bf2f(k1[j]);
        s[g] = acc;
    }
#pragma unroll
    for (int m = 1; m <= 2; m <<= 1)
#pragma unroll
        for (int g = 0; g < 16; ++g)
            s[g] += __shfl_xor(s[g], m, 64);

    float mx = s[0];
#pragma unroll
    for (int g = 1; g < 16; ++g) mx = fmaxf(mx, s[g]);
    float p[16], denom = 0.f;
#pragma unroll
    for (int g = 0; g < 16; ++g) {
        p[g] = __expf((s[g] - mx) * 0.125f);
        denom += p[g];
    }
    float inv = 1.f / denom;

    float f[16];
#pragma unroll
    for (int j = 0; j < 16; ++j) f[j] = 0.f;
#pragma unroll
    for (int g = 0; g < 16; ++g) {
        float pg = p[g] * inv;
        const ushort8v v0 = *reinterpret_cast<const ushort8v*>(&VL[wid][g * 64 + sub * 16]);
        const ushort8v v1 = *reinterpret_cast<const ushort8v*>(&VL[wid][g * 64 + sub * 16 + 8]);
#pragma unroll
        for (int j = 0; j < 8; ++j) {
            f[j]     += pg * bf2f(v0[j]);
            f[8 + j] += pg * bf2f(v1[j]);
        }
    }
    ushort8v o0, o1;
#pragma unroll
    for (int j = 0; j < 8; ++j) { o0[j] = f2bf(f[j]); o1[j] = f2bf(f[8 + j]); }
    *reinterpret_cast<ushort8v*>(&Fb[base + off])     = o0;
    *reinterpret_cast<ushort8v*>(&Fb[base + off + 8]) = o1;
}

// ---------------------------------------------------------------------------
extern "C" void kernel_launch(void* const* d_in, const int* in_sizes, int n_in,
                              void* d_out, int out_size, void* d_ws, size_t ws_size,
                              hipStream_t stream)
{
    (void)in_sizes; (void)n_in; (void)out_size; (void)ws_size;
    const float* latent = (const float*)d_in[0];
    const float* cond   = (const float*)d_in[1];
    const float* Wq     = (const float*)d_in[2];
    const float* Wk     = (const float*)d_in[3];
    const float* Wv     = (const float*)d_in[4];
    const float* Wout   = (const float*)d_in[5];
    const float* bout   = (const float*)d_in[6];
    float* out = (float*)d_out;

    char* ws = (char*)d_ws;
    const size_t MB = 1ull << 20;
    unsigned short* wqb = (unsigned short*)(ws + 0 * MB);
    unsigned short* wkb = (unsigned short*)(ws + 2 * MB);
    unsigned short* wvb = (unsigned short*)(ws + 4 * MB);
    unsigned short* wob = (unsigned short*)(ws + 6 * MB);
    unsigned short* Qb  = (unsigned short*)(ws + 8 * MB);              // 128 MB, becomes feats
    unsigned short* Kbf = (unsigned short*)(ws + 8 * MB + 128 * MB);   // 128 MB
    unsigned short* Vbf = (unsigned short*)(ws + 8 * MB + 256 * MB);   // 128 MB
    unsigned short* Lb  = (unsigned short*)(ws + 8 * MB + 384 * MB);   // 128 MB latent bf16
    unsigned short* Cb  = (unsigned short*)(ws + 8 * MB + 512 * MB);   // 128 MB cond bf16

    const int wn4 = (KDIM * NDIM) / 4;
    f32_to_bf16_k<<<1024, 256, 0, stream>>>(Wq,   wqb, wn4);
    f32_to_bf16_k<<<1024, 256, 0, stream>>>(Wk,   wkb, wn4);
    f32_to_bf16_k<<<1024, 256, 0, stream>>>(Wv,   wvb, wn4);
    f32_to_bf16_k<<<1024, 256, 0, stream>>>(Wout, wob, wn4);

    const int an4 = (NB * KDIM) / 4;
    f32_to_bf16_k<<<4096, 256, 0, stream>>>(latent, Lb, an4);
    f32_to_bf16_k<<<4096, 256, 0, stream>>>(cond,   Cb, an4);

    const int nblk = (NB / BM) * (NDIM / BN);   // 256 * 4 = 1024
    gemm256<0><<<nblk, 512, 0, stream>>>(Lb, wqb, nullptr, Qb);
    gemm256<0><<<nblk, 512, 0, stream>>>(Cb, wkb, nullptr, Kbf);
    gemm256<0><<<nblk, 512, 0, stream>>>(Cb, wvb, nullptr, Vbf);

    attn_k<<<NB / 4, 256, 0, stream>>>(Qb, Kbf, Vbf, Qb);

    gemm256<1><<<nblk, 512, 0, stream>>>(Qb, wob, bout, out);
}